// Round 4
// baseline (210.941 us; speedup 1.0000x reference)
//
#include <hip/hip_runtime.h>
#include <hip/hip_cooperative_groups.h>

namespace cg = cooperative_groups;

// ---------------------------------------------------------------------------
// AdaptiveMetaLearnerV2 — single cooperative kernel.
// Phase 1: tabulate (Phi(t), Psi(t)) at TABN nodes, ONE WAVE PER ENTRY
//          (lane-parallel matvecs, butterfly-shuffle LN stats).
// grid.sync()
// Phase 2: per-point linear interp in t = x/(|x|*std(w1)+eps), block-reduced
//          sigmoid mean via one atomic per block.
// TABN = grid_waves = 4096 (interp error ~1e-5 << 9.9e-3 threshold; absmax
// was bit-identical between direct eval and 8192-entry interp).
// ---------------------------------------------------------------------------

#define LSTM_H 20
#define LSTM_G 80
#define LN_EPS 1e-5f
#define TABN 4096
#define XBIG 1e6f
#define NBLK 1024
#define NTHR 256

struct Params {
    const float *x, *w1, *b1, *g1, *be1;
    const float *wi0, *gi0, *bi0, *bh0, *gc0, *bc0;
    const float *wi1, *gi1, *bi1, *bh1, *gc1, *bc1;
    const float *wo, *bo, *wa, *ba;
    float *out, *qt;
    float2 *tab;
    int n;
};

__device__ __forceinline__ float rcp_f(float x) { return __builtin_amdgcn_rcpf(x); }
__device__ __forceinline__ float sigm_f(float x) { return rcp_f(1.0f + __expf(-x)); }
__device__ __forceinline__ float tanh_f(float x) {
    return 1.0f - 2.0f * rcp_f(__expf(2.0f * x) + 1.0f);
}

// ---- one LN-LSTM cell, wave-parallel; xin[20] replicated in regs ----
__device__ __forceinline__ void cell_wave(
    float* xin, float* W, int lane,
    const float* __restrict__ wi, const float* __restrict__ gi,
    const float* __restrict__ bi, const float* __restrict__ bh,
    const float* __restrict__ gc, const float* __restrict__ bc)
{
    const int r0 = lane;
    const int r1 = 64 + (lane & 15);
    const bool has1 = lane < 16;

    float g0 = 0.f, g1v = 0.f;
#pragma unroll
    for (int h = 0; h < LSTM_H; h += 4) {
        float4 w4 = *reinterpret_cast<const float4*>(wi + r0 * LSTM_H + h);
        g0 = fmaf(xin[h],     w4.x, g0);
        g0 = fmaf(xin[h + 1], w4.y, g0);
        g0 = fmaf(xin[h + 2], w4.z, g0);
        g0 = fmaf(xin[h + 3], w4.w, g0);
    }
#pragma unroll
    for (int h = 0; h < LSTM_H; h += 4) {
        float4 w4 = *reinterpret_cast<const float4*>(wi + r1 * LSTM_H + h);
        g1v = fmaf(xin[h],     w4.x, g1v);
        g1v = fmaf(xin[h + 1], w4.y, g1v);
        g1v = fmaf(xin[h + 2], w4.z, g1v);
        g1v = fmaf(xin[h + 3], w4.w, g1v);
    }
    if (!has1) g1v = 0.f;

    // LN-80: butterfly over 64 lanes, two-pass
    float s = g0 + g1v;
#pragma unroll
    for (int off = 1; off < 64; off <<= 1) s += __shfl_xor(s, off, 64);
    float m = s * (1.0f / LSTM_G);
    float d0 = g0 - m;
    float d1 = has1 ? g1v - m : 0.f;
    float q = fmaf(d0, d0, d1 * d1);
#pragma unroll
    for (int off = 1; off < 64; off <<= 1) q += __shfl_xor(q, off, 64);
    float inv = rcp_f(sqrtf(q * (1.0f / (LSTM_G - 1))) + LN_EPS);

    W[r0] = d0 * inv * gi[r0] + (bi[r0] + bh[r0]);
    if (has1) W[r1] = d1 * inv * gi[r1] + (bi[r1] + bh[r1]);

    const bool lh = lane < LSTM_H;
    const int h = lh ? lane : 0;
    float zi = W[h];
    float zo = W[40 + h];
    float zg = W[60 + h];
    float cv = sigm_f(zi) * tanh_f(zg);   // cx == 0: f-gate dead
    float ov = sigm_f(zo);
    if (!lh) cv = 0.f;

    // LN-20 over c (32-lane-group butterfly; lanes 0..19 live)
    float s2 = cv;
#pragma unroll
    for (int off = 1; off < 32; off <<= 1) s2 += __shfl_xor(s2, off, 64);
    float m2 = s2 * (1.0f / LSTM_H);
    float d2 = lh ? cv - m2 : 0.f;
    float q2 = d2 * d2;
#pragma unroll
    for (int off = 1; off < 32; off <<= 1) q2 += __shfl_xor(q2, off, 64);
    float inv2 = rcp_f(sqrtf(q2 * (1.0f / (LSTM_H - 1))) + LN_EPS);

    float ho = ov * tanh_f(d2 * inv2 * gc[h] + bc[h]);
    if (lh) W[80 + lane] = ho;

#pragma unroll
    for (int hh = 0; hh < LSTM_H; hh += 4) {
        float4 v = *reinterpret_cast<const float4*>(&W[80 + hh]);
        xin[hh] = v.x; xin[hh + 1] = v.y; xin[hh + 2] = v.z; xin[hh + 3] = v.w;
    }
}

__global__ void __launch_bounds__(NTHR, 4) fused(Params P)
{
    const int wid  = threadIdx.x >> 6;
    const int lane = threadIdx.x & 63;

    __shared__ float lds[4][104];
    float* W = lds[wid];

    // ---- uniform w1 stats (every thread, stays in SGPRs) ----
    float mw = 0.f;
#pragma unroll
    for (int h = 0; h < LSTM_H; ++h) mw += P.w1[h];
    mw *= (1.0f / LSTM_H);
    float ss = 0.f;
#pragma unroll
    for (int h = 0; h < LSTM_H; ++h) {
        float d = P.w1[h] - mw;
        ss = fmaf(d, d, ss);
    }
    float sw = sqrtf(ss * (1.0f / (LSTM_H - 1)));
    float T = 1.0f / sw;
    float inv_dt = (float)(TABN - 1) / (2.0f * T);
    float dt = 2.0f * T / (float)(TABN - 1);

    // ================= phase 1: build table, 1 entry per wave =============
    {
        const int j = blockIdx.x * 4 + wid;       // TABN == NBLK*4
        float t = fmaf((float)j, dt, -T);
        float den = 1.0f - fabsf(t) * sw;         // invert t = x/(|x|sw+eps)
        float xv = (den < 1e-9f) ? copysignf(XBIG, t) : LN_EPS * t * rcp_f(den);
        if (fabsf(xv) > XBIG) xv = copysignf(XBIG, t);

        // layer 1: 1->20 affine, LN-20, tanh
        const bool lh = lane < LSTM_H;
        const int h0 = lh ? lane : 0;
        float av = lh ? fmaf(xv, P.w1[h0], P.b1[h0]) : 0.f;
        float s = av;
#pragma unroll
        for (int off = 1; off < 32; off <<= 1) s += __shfl_xor(s, off, 64);
        float m = s * (1.0f / LSTM_H);
        float d = lh ? av - m : 0.f;
        float q = d * d;
#pragma unroll
        for (int off = 1; off < 32; off <<= 1) q += __shfl_xor(q, off, 64);
        float inv = rcp_f(sqrtf(q * (1.0f / (LSTM_H - 1))) + LN_EPS);
        if (lh) W[80 + lane] = tanh_f(d * inv * P.g1[h0] + P.be1[h0]);

        float xin[LSTM_H];
#pragma unroll
        for (int hh = 0; hh < LSTM_H; hh += 4) {
            float4 v = *reinterpret_cast<const float4*>(&W[80 + hh]);
            xin[hh] = v.x; xin[hh + 1] = v.y; xin[hh + 2] = v.z; xin[hh + 3] = v.w;
        }

        cell_wave(xin, W, lane, P.wi0, P.gi0, P.bi0, P.bh0, P.gc0, P.bc0);
        cell_wave(xin, W, lane, P.wi1, P.gi1, P.bi1, P.bh1, P.gc1, P.bc1);

        float xo = P.bo[0];
        float qa = P.ba[0];
#pragma unroll
        for (int hh = 0; hh < LSTM_H; ++hh) {
            xo = fmaf(xin[hh], P.wo[hh], xo);
            qa = fmaf(xin[hh], P.wa[hh], qa);
        }
        if (lane == 0) P.tab[j] = make_float2(xo, sigm_f(qa));
        if (blockIdx.x == 0 && threadIdx.x == 0) *P.qt = 0.f;
    }

    __threadfence();          // release tab/qt device-wide before grid sync
    cg::this_grid().sync();

    // ================= phase 2: per-point interp, 4 pts/thread =============
    {
        const int tid = blockIdx.x * NTHR + threadIdx.x;
        const int base = tid * 4;
        const int n = P.n;
        float qsum = 0.f;

        auto interp1 = [&](float xc, float& oc) {
            float t = xc * rcp_f(fabsf(xc) * sw + LN_EPS);
            float u = (t + T) * inv_dt;
            u = fminf(fmaxf(u, 0.0f), (float)(TABN - 1) - 1e-3f);
            int k = (int)u;
            float f = u - (float)k;
            float2 e0 = P.tab[k];
            float2 e1 = P.tab[k + 1];
            oc = fmaf(f, e1.x - e0.x, e0.x);
            return fmaf(f, e1.y - e0.y, e0.y);
        };

        if (base + 3 < n) {
            float4 xv = *reinterpret_cast<const float4*>(P.x + base);
            float4 ov;
            qsum += interp1(xv.x, ov.x);
            qsum += interp1(xv.y, ov.y);
            qsum += interp1(xv.z, ov.z);
            qsum += interp1(xv.w, ov.w);
            *reinterpret_cast<float4*>(P.out + base) = ov;
        } else if (base < n) {
            for (int i = base; i < n; ++i) {
                float oc;
                qsum += interp1(P.x[i], oc);
                P.out[i] = oc;
            }
        }

#pragma unroll
        for (int off = 32; off > 0; off >>= 1)
            qsum += __shfl_down(qsum, off, 64);

        __shared__ float wsum[4];
        if (lane == 0) wsum[wid] = qsum;
        __syncthreads();
        if (threadIdx.x == 0) {
            float stot = wsum[0] + wsum[1] + wsum[2] + wsum[3];
            atomicAdd(P.qt, stot * (1.0f / (float)n));
        }
    }
}

extern "C" void kernel_launch(void* const* d_in, const int* in_sizes, int n_in,
                              void* d_out, int out_size, void* d_ws, size_t ws_size,
                              hipStream_t stream) {
    Params P;
    P.x   = (const float*)d_in[0];
    P.w1  = (const float*)d_in[1];
    P.b1  = (const float*)d_in[2];
    P.g1  = (const float*)d_in[3];
    P.be1 = (const float*)d_in[4];
    P.wi0 = (const float*)d_in[5];
    P.gi0 = (const float*)d_in[7];
    P.bi0 = (const float*)d_in[8];
    P.bh0 = (const float*)d_in[10];
    P.gc0 = (const float*)d_in[11];
    P.bc0 = (const float*)d_in[12];
    P.wi1 = (const float*)d_in[13];
    P.gi1 = (const float*)d_in[15];
    P.bi1 = (const float*)d_in[16];
    P.bh1 = (const float*)d_in[18];
    P.gc1 = (const float*)d_in[19];
    P.bc1 = (const float*)d_in[20];
    P.wo  = (const float*)d_in[21];
    P.bo  = (const float*)d_in[22];
    P.wa  = (const float*)d_in[23];
    P.ba  = (const float*)d_in[24];

    const int n = in_sizes[0];
    P.n = n;
    P.out = (float*)d_out;
    P.qt  = P.out + n;
    P.tab = (float2*)d_ws;

    void* args[] = { &P };
    hipLaunchCooperativeKernel(reinterpret_cast<void*>(fused),
                               dim3(NBLK), dim3(NTHR), args, 0, stream);
}

// Round 5
// 27.554 us; speedup vs baseline: 7.6556x; 7.6556x over previous
//
#include <hip/hip_runtime.h>

// ---------------------------------------------------------------------------
// AdaptiveMetaLearnerV2 — table-lookup, two kernels, no memset node.
//
// With b1==0 the layer-1 LN output is t*(w1_h - mean(w1)) with
//   t = x / (|x|*std(w1,ddof=1) + eps)  in (-1/sw, 1/sw),
// so (x_out, sigmoid(q)) = (Phi(t), Psi(t)) — smooth scalar functions of t.
// Kernel A: tabulate at TABN nodes, ONE WAVE PER ENTRY (lane-parallel
//           matvecs, butterfly LN stats); block 0 also zeroes qt.
// Kernel B: per-point linear interp (memory-bound), block-reduced qt atomic.
// Cooperative grid.sync variant measured 200us (VALUBusy 2.3%) — reverted.
// ---------------------------------------------------------------------------

#define LSTM_H 20
#define LSTM_G 80
#define LN_EPS 1e-5f
#define TABN 4096
#define XBIG 1e6f

__device__ __forceinline__ float rcp_f(float x) { return __builtin_amdgcn_rcpf(x); }
__device__ __forceinline__ float sigm_f(float x) { return rcp_f(1.0f + __expf(-x)); }
__device__ __forceinline__ float tanh_f(float x) {
    return 1.0f - 2.0f * rcp_f(__expf(2.0f * x) + 1.0f);
}

// uniform w1 stats -> sw (std, ddof=1); stays in scalar registers
__device__ __forceinline__ float w1_std(const float* __restrict__ w1) {
    float mw = 0.f;
#pragma unroll
    for (int h = 0; h < LSTM_H; ++h) mw += w1[h];
    mw *= (1.0f / LSTM_H);
    float ss = 0.f;
#pragma unroll
    for (int h = 0; h < LSTM_H; ++h) {
        float d = w1[h] - mw;
        ss = fmaf(d, d, ss);
    }
    return sqrtf(ss * (1.0f / (LSTM_H - 1)));
}

// ---- one LN-LSTM cell, wave-parallel; xin[20] replicated in regs ----
__device__ __forceinline__ void cell_wave(
    float* xin, float* W, int lane,
    const float* __restrict__ wi, const float* __restrict__ gi,
    const float* __restrict__ bi, const float* __restrict__ bh,
    const float* __restrict__ gc, const float* __restrict__ bc)
{
    const int r0 = lane;
    const int r1 = 64 + (lane & 15);
    const bool has1 = lane < 16;

    float g0 = 0.f, g1v = 0.f;
#pragma unroll
    for (int h = 0; h < LSTM_H; h += 4) {
        float4 w4 = *reinterpret_cast<const float4*>(wi + r0 * LSTM_H + h);
        g0 = fmaf(xin[h],     w4.x, g0);
        g0 = fmaf(xin[h + 1], w4.y, g0);
        g0 = fmaf(xin[h + 2], w4.z, g0);
        g0 = fmaf(xin[h + 3], w4.w, g0);
    }
#pragma unroll
    for (int h = 0; h < LSTM_H; h += 4) {
        float4 w4 = *reinterpret_cast<const float4*>(wi + r1 * LSTM_H + h);
        g1v = fmaf(xin[h],     w4.x, g1v);
        g1v = fmaf(xin[h + 1], w4.y, g1v);
        g1v = fmaf(xin[h + 2], w4.z, g1v);
        g1v = fmaf(xin[h + 3], w4.w, g1v);
    }
    if (!has1) g1v = 0.f;

    // LN-80 stats, two-pass butterfly over 64 lanes
    float s = g0 + g1v;
#pragma unroll
    for (int off = 1; off < 64; off <<= 1) s += __shfl_xor(s, off, 64);
    float m = s * (1.0f / LSTM_G);
    float d0 = g0 - m;
    float d1 = has1 ? g1v - m : 0.f;
    float q = fmaf(d0, d0, d1 * d1);
#pragma unroll
    for (int off = 1; off < 64; off <<= 1) q += __shfl_xor(q, off, 64);
    float inv = rcp_f(sqrtf(q * (1.0f / (LSTM_G - 1))) + LN_EPS);

    W[r0] = d0 * inv * gi[r0] + (bi[r0] + bh[r0]);
    if (has1) W[r1] = d1 * inv * gi[r1] + (bi[r1] + bh[r1]);

    const bool lh = lane < LSTM_H;
    const int h = lh ? lane : 0;
    float zi = W[h];
    float zo = W[40 + h];
    float zg = W[60 + h];
    float cv = sigm_f(zi) * tanh_f(zg);   // cx == 0: f-gate dead
    float ov = sigm_f(zo);
    if (!lh) cv = 0.f;

    // LN-20 over c (32-lane-group butterfly; lanes 0..19 live)
    float s2 = cv;
#pragma unroll
    for (int off = 1; off < 32; off <<= 1) s2 += __shfl_xor(s2, off, 64);
    float m2 = s2 * (1.0f / LSTM_H);
    float d2 = lh ? cv - m2 : 0.f;
    float q2 = d2 * d2;
#pragma unroll
    for (int off = 1; off < 32; off <<= 1) q2 += __shfl_xor(q2, off, 64);
    float inv2 = rcp_f(sqrtf(q2 * (1.0f / (LSTM_H - 1))) + LN_EPS);

    float ho = ov * tanh_f(d2 * inv2 * gc[h] + bc[h]);
    if (lh) W[80 + lane] = ho;

#pragma unroll
    for (int hh = 0; hh < LSTM_H; hh += 4) {
        float4 v = *reinterpret_cast<const float4*>(&W[80 + hh]);
        xin[hh] = v.x; xin[hh + 1] = v.y; xin[hh + 2] = v.z; xin[hh + 3] = v.w;
    }
}

// ---- Kernel A: build (Phi, Psi) table, one wave per entry; zero qt ----
__global__ void __launch_bounds__(256) build_table(
    const float* __restrict__ w1, const float* __restrict__ b1,
    const float* __restrict__ g1, const float* __restrict__ be1,
    const float* __restrict__ wi0, const float* __restrict__ gi0,
    const float* __restrict__ bi0, const float* __restrict__ bh0,
    const float* __restrict__ gc0, const float* __restrict__ bc0,
    const float* __restrict__ wi1, const float* __restrict__ gi1,
    const float* __restrict__ bi1, const float* __restrict__ bh1,
    const float* __restrict__ gc1, const float* __restrict__ bc1,
    const float* __restrict__ wo, const float* __restrict__ bo,
    const float* __restrict__ wa, const float* __restrict__ ba,
    float2* __restrict__ tab, float* __restrict__ qt)
{
    const int wid  = threadIdx.x >> 6;
    const int lane = threadIdx.x & 63;
    const int j = blockIdx.x * 4 + wid;       // TABN == gridDim.x * 4

    __shared__ float lds[4][104];
    float* W = lds[wid];

    float sw = w1_std(w1);
    float T = 1.0f / sw;
    float dt = 2.0f * T / (float)(TABN - 1);
    float t = fmaf((float)j, dt, -T);

    float den = 1.0f - fabsf(t) * sw;          // invert t = x/(|x|sw+eps)
    float xv = (den < 1e-9f) ? copysignf(XBIG, t) : LN_EPS * t * rcp_f(den);
    if (fabsf(xv) > XBIG) xv = copysignf(XBIG, t);

    // layer 1: 1->20 affine, LN-20, tanh (lane-parallel)
    const bool lh = lane < LSTM_H;
    const int h0 = lh ? lane : 0;
    float av = lh ? fmaf(xv, w1[h0], b1[h0]) : 0.f;
    float s = av;
#pragma unroll
    for (int off = 1; off < 32; off <<= 1) s += __shfl_xor(s, off, 64);
    float m = s * (1.0f / LSTM_H);
    float d = lh ? av - m : 0.f;
    float q = d * d;
#pragma unroll
    for (int off = 1; off < 32; off <<= 1) q += __shfl_xor(q, off, 64);
    float inv = rcp_f(sqrtf(q * (1.0f / (LSTM_H - 1))) + LN_EPS);
    if (lh) W[80 + lane] = tanh_f(d * inv * g1[h0] + be1[h0]);

    float xin[LSTM_H];
#pragma unroll
    for (int hh = 0; hh < LSTM_H; hh += 4) {
        float4 v = *reinterpret_cast<const float4*>(&W[80 + hh]);
        xin[hh] = v.x; xin[hh + 1] = v.y; xin[hh + 2] = v.z; xin[hh + 3] = v.w;
    }

    cell_wave(xin, W, lane, wi0, gi0, bi0, bh0, gc0, bc0);
    cell_wave(xin, W, lane, wi1, gi1, bi1, bh1, gc1, bc1);

    float xo = bo[0];
    float qa = ba[0];
#pragma unroll
    for (int hh = 0; hh < LSTM_H; ++hh) {
        xo = fmaf(xin[hh], wo[hh], xo);
        qa = fmaf(xin[hh], wa[hh], qa);
    }
    if (lane == 0) tab[j] = make_float2(xo, sigm_f(qa));
    if (blockIdx.x == 0 && threadIdx.x == 0) *qt = 0.f;  // replaces memset node
}

// ---- Kernel B: per-point interp, 4 points/thread ----
__global__ void eval_points(
    const float* __restrict__ x,
    const float* __restrict__ w1,
    const float2* __restrict__ tab,
    float* __restrict__ out,
    float* __restrict__ qt,
    int n)
{
    const int tid = blockIdx.x * blockDim.x + threadIdx.x;
    const int base = tid * 4;

    float sw = w1_std(w1);              // uniform, recomputed (no hdr dep)
    float T = 1.0f / sw;
    float inv_dt = (float)(TABN - 1) / (2.0f * T);

    float qsum = 0.f;

    auto interp1 = [&](float xc, float& oc) {
        float t = xc * rcp_f(fabsf(xc) * sw + LN_EPS);
        float u = (t + T) * inv_dt;
        u = fminf(fmaxf(u, 0.0f), (float)(TABN - 1) - 1e-3f);
        int k = (int)u;
        float f = u - (float)k;
        float2 e0 = tab[k];
        float2 e1 = tab[k + 1];
        oc = fmaf(f, e1.x - e0.x, e0.x);
        return fmaf(f, e1.y - e0.y, e0.y);
    };

    if (base + 3 < n) {
        float4 xv = *reinterpret_cast<const float4*>(x + base);
        float4 ov;
        qsum += interp1(xv.x, ov.x);
        qsum += interp1(xv.y, ov.y);
        qsum += interp1(xv.z, ov.z);
        qsum += interp1(xv.w, ov.w);
        *reinterpret_cast<float4*>(out + base) = ov;
    } else if (base < n) {
        for (int i = base; i < n; ++i) {
            float oc;
            qsum += interp1(x[i], oc);
            out[i] = oc;
        }
    }

#pragma unroll
    for (int off = 32; off > 0; off >>= 1)
        qsum += __shfl_down(qsum, off, 64);

    __shared__ float wsum[4];
    int lane = threadIdx.x & 63;
    int wid = threadIdx.x >> 6;
    if (lane == 0) wsum[wid] = qsum;
    __syncthreads();
    if (threadIdx.x == 0) {
        float stot = wsum[0] + wsum[1] + wsum[2] + wsum[3];
        atomicAdd(qt, stot * (1.0f / (float)n));
    }
}

extern "C" void kernel_launch(void* const* d_in, const int* in_sizes, int n_in,
                              void* d_out, int out_size, void* d_ws, size_t ws_size,
                              hipStream_t stream) {
    const float* x   = (const float*)d_in[0];
    const float* w1  = (const float*)d_in[1];
    const float* b1  = (const float*)d_in[2];
    const float* g1  = (const float*)d_in[3];
    const float* be1 = (const float*)d_in[4];
    const float* wi0 = (const float*)d_in[5];
    const float* gi0 = (const float*)d_in[7];
    const float* bi0 = (const float*)d_in[8];
    const float* bh0 = (const float*)d_in[10];
    const float* gc0 = (const float*)d_in[11];
    const float* bc0 = (const float*)d_in[12];
    const float* wi1 = (const float*)d_in[13];
    const float* gi1 = (const float*)d_in[15];
    const float* bi1 = (const float*)d_in[16];
    const float* bh1 = (const float*)d_in[18];
    const float* gc1 = (const float*)d_in[19];
    const float* bc1 = (const float*)d_in[20];
    const float* wo  = (const float*)d_in[21];
    const float* bo  = (const float*)d_in[22];
    const float* wa  = (const float*)d_in[23];
    const float* ba  = (const float*)d_in[24];

    const int n = in_sizes[0];
    float* out = (float*)d_out;
    float* qt  = out + n;
    float2* tab = (float2*)d_ws;

    build_table<<<TABN / 4, 256, 0, stream>>>(
        w1, b1, g1, be1,
        wi0, gi0, bi0, bh0, gc0, bc0,
        wi1, gi1, bi1, bh1, gc1, bc1,
        wo, bo, wa, ba, tab, qt);

    const int block = 256;
    const int pts_per_thread = 4;
    const int threads = (n + pts_per_thread - 1) / pts_per_thread;
    const int grid = (threads + block - 1) / block;
    eval_points<<<grid, block, 0, stream>>>(x, w1, tab, out, qt, n);
}